// Round 2
// 516.490 us; speedup vs baseline: 1.1981x; 1.1981x over previous
//
#include <hip/hip_runtime.h>
#include <cstdint>
#include <cmath>

typedef _Float16 half4v __attribute__((ext_vector_type(4)));
typedef _Float16 half8v __attribute__((ext_vector_type(8)));
typedef unsigned short ushort8v __attribute__((ext_vector_type(8)));
typedef float float4v __attribute__((ext_vector_type(4)));

#define NB 16
#define NC 256
#define HW 9216   // 96*96

// ---------------------------------------------------------------------------
// Stage 1: y = dec+skip; z = 3y + w_fea*w_edge(y) + DoG(y).
// zt layout is plain [b][c][hw] f16 (contiguous per channel) -> no zb LDS.
// LDS 72576 B -> 2 blocks/CU (was 142848 -> 1 block/CU).
// ---------------------------------------------------------------------------
__global__ __launch_bounds__(512) void stage1_kernel(
    const float* __restrict__ skip, const float* __restrict__ dec,
    const float* __restrict__ wfea, const float* __restrict__ sig1,
    const float* __restrict__ sig2, _Float16* __restrict__ zt) {
    __shared__ __align__(16) float sy[HW];          // 36864 B
    __shared__ float d72b[72 * 72];                 // 20736 B
    __shared__ float d48b[48 * 48];                 //  9216 B
    __shared__ float d24b[24 * 24];                 //  2304 B
    __shared__ int   tIA[3][96];                    //  1152 B
    __shared__ int   tIB[3][96];                    //  1152 B
    __shared__ float tFR[3][96];                    //  1152 B  total 72576 B

    const int tid = threadIdx.x;
    const int b = blockIdx.x >> 6;
    const int cg = blockIdx.x & 63;

    // bilinear index/weight tables (once per block; replaces per-pixel floorf/clamp)
    for (int i = tid; i < 288; i += 512) {
        int s = i / 96, v = i - s * 96;
        float sf = (s == 0) ? 0.25f : (s == 1 ? 0.5f : 0.75f);
        float of = (s == 0) ? 0.375f : (s == 1 ? 0.25f : 0.125f);
        int S = (s == 0) ? 24 : (s == 1 ? 48 : 72);
        float src = (float)v * sf - of;
        float f0 = floorf(src);
        int i0 = (int)f0;
        tFR[s][v] = src - f0;
        tIA[s][v] = i0 < 0 ? 0 : i0;
        tIB[s][v] = (i0 + 1 > S - 1) ? S - 1 : i0 + 1;
    }

    for (int cc = 0; cc < 4; ++cc) {
        const int c = cg * 4 + cc;
        const size_t base = ((size_t)b * NC + c) * HW;
        __syncthreads();   // previous channel done reading sy/d*; tables visible
        // ---- load y = dec + skip (float4) ----
        const float4* dp = (const float4*)(dec + base);
        const float4* sp = (const float4*)(skip + base);
        for (int i = tid; i < HW / 4; i += 512) {
            float4 a = dp[i], s = sp[i];
            float4 v = make_float4(a.x + s.x, a.y + s.y, a.z + s.z, a.w + s.w);
            *(float4*)&sy[i * 4] = v;
        }
        __syncthreads();
        // ---- downsamples ----
        // 96->48: src=2o+0.5 -> avg of cols/rows (2o,2o+1)
        for (int i = tid; i < 48 * 48; i += 512) {
            int oy = i / 48, ox = i - oy * 48;
            const float* r = &sy[oy * 192 + ox * 2];
            d48b[i] = 0.25f * (r[0] + r[1] + r[96] + r[97]);
        }
        // 96->24: src=4o+1.5 -> avg of (4o+1,4o+2)
        for (int i = tid; i < 24 * 24; i += 512) {
            int oy = i / 24, ox = i - oy * 24;
            const float* r = &sy[(4 * oy + 1) * 96 + 4 * ox + 1];
            d24b[i] = 0.25f * (r[0] + r[1] + r[96] + r[97]);
        }
        // 96->72: src=(8o+1)/6 -> i0 = 4*(o/3)+(o%3), f in {1/6,1/2,5/6}
        for (int i = tid; i < 72 * 72; i += 512) {
            int oy = i / 72, ox = i - oy * 72;
            int qy = oy / 3, ry = oy - qy * 3;
            int qx = ox / 3, rx = ox - qx * 3;
            int iy = 4 * qy + ry, ix = 4 * qx + rx;
            float fy = (ry == 0) ? 0.16666667f : (ry == 1 ? 0.5f : 0.83333333f);
            float fx = (rx == 0) ? 0.16666667f : (rx == 1 ? 0.5f : 0.83333333f);
            const float* r0 = &sy[iy * 96 + ix];
            float v0 = r0[0] + fx * (r0[1] - r0[0]);
            float v1 = r0[96] + fx * (r0[97] - r0[96]);
            d72b[i] = v0 + fy * (v1 - v0);
        }
        // ---- per-channel params ----
        float wf = wfea[c];
        float sgA = 2.f / (1.f + expf(-sig1[c]));
        float sgB = 2.f / (1.f + expf(-sig2[c]));
        float eA = expf(-0.5f / (sgA * sgA));
        float eB = expf(-0.5f / (sgB * sgB));
        float nA = 1.f + 4.f * eA + 4.f * eA * eA;
        float nB = 1.f + 4.f * eB + 4.f * eB * eB;
        float k0 = 1.f / nA - 1.f / nB;
        float k1 = eA / nA - eB / nB;
        float k2 = eA * eA / nA - eB * eB / nB;
        __syncthreads();
        // ---- per-pixel: upsample (table-driven), edges, DoG, z ----
        auto bil = [&](const float* d, int S, int si, int hh, int xx) -> float {
            int ya = tIA[si][hh] * S, yb = tIB[si][hh] * S;
            float fy = tFR[si][hh];
            int xa = tIA[si][xx], xb = tIB[si][xx];
            float fx = tFR[si][xx];
            float a = d[ya + xa], bb = d[ya + xb];
            float cv = d[yb + xa], e = d[yb + xb];
            float t = a + fx * (bb - a);
            float u = cv + fx * (e - cv);
            return t + fy * (u - t);
        };
        for (int p = tid; p < HW; p += 512) {
            int h = p / 96, x = p - h * 96;
            float yv = sy[p];
            float u24 = bil(d24b, 24, 0, h, x);
            float u48 = bil(d48b, 48, 1, h, x);
            float u72 = bil(d72b, 72, 2, h, x);
            float e0 = fabsf(yv - u24);
            float e1 = fabsf(yv - u48);
            float e2 = fabsf(yv - u72);
            float we = (fabsf(e0 - e1) + fabsf(e0 - e2) + fabsf(e1 - e2)) * (1.f / 3.f);
            // DoG (zero-padded 3x3, combined g1-g2 kernel)
            float up = (h > 0) ? sy[p - 96] : 0.f;
            float dn = (h < 95) ? sy[p + 96] : 0.f;
            float lf = (x > 0) ? sy[p - 1] : 0.f;
            float rt = (x < 95) ? sy[p + 1] : 0.f;
            float ul = (h > 0 && x > 0) ? sy[p - 97] : 0.f;
            float ur = (h > 0 && x < 95) ? sy[p - 95] : 0.f;
            float dl = (h < 95 && x > 0) ? sy[p + 95] : 0.f;
            float dr = (h < 95 && x < 95) ? sy[p + 97] : 0.f;
            float dog = k0 * yv + k1 * (up + dn + lf + rt) + k2 * (ul + ur + dl + dr);
            float z = 3.f * yv + wf * we + dog;
            zt[base + p] = (_Float16)z;   // contiguous 2B stores, coalesced
        }
    }
}

// ---------------------------------------------------------------------------
// Stage 2: out[b,o,n] = sum_c W[o,c] * z[b,c,n] + skip[b,o,n]
// f16 MFMA 16x16x32. 256 thr = 4 waves (2m x 2n), BM=128 BN=64 BK=64.
// LDS 27648 B, acc 32 VGPR -> 4 resident blocks/CU for latency overlap.
// Bs is [n][k] (pad 72, XOR-swizzled) so B-fragments are straight ds_read_b128.
// ---------------------------------------------------------------------------
__global__ __launch_bounds__(256, 4) void gemm_kernel(
    const _Float16* __restrict__ zt, const float* __restrict__ W,
    const float* __restrict__ skip, float* __restrict__ out) {
    __shared__ __align__(16) _Float16 As[128 * 72];   // W tile [m][k], pad 72: 18432 B
    __shared__ __align__(16) _Float16 Bs[64 * 72];    // z tile [n][k], pad 72:  9216 B

    const int tid = threadIdx.x;
    const int bid = blockIdx.x;
    const int ni = bid % 144;                // 9216/64 n-tiles
    const int mi = (bid / 144) & 1;          // 2 m-tiles
    const int b  = bid / 288;
    const int n0 = ni * 64;
    const int m0 = mi * 128;
    const int lane = tid & 63;
    const int w = tid >> 6;                  // 0..3
    const int wm = (w & 1) * 64;
    const int wn = (w >> 1) * 32;
    const int l15 = lane & 15;
    const int quad = lane >> 4;

    float4v acc[4][2];
    #pragma unroll
    for (int i = 0; i < 4; ++i)
        #pragma unroll
        for (int j = 0; j < 2; ++j)
            acc[i][j] = (float4v){0.f, 0.f, 0.f, 0.f};

    for (int kt = 0; kt < 4; ++kt) {
        const int kb = kt * 64;
        __syncthreads();
        // stage A: W[m0:m0+128][kb:kb+64] f32 -> f16, [m][k] pad 72
        #pragma unroll
        for (int p = 0; p < 8; ++p) {
            int idx = tid + p * 256;            // 0..2047
            int row = idx >> 4, c4 = (idx & 15) << 2;
            float4 wv = *(const float4*)&W[(m0 + row) * 256 + kb + c4];
            half4v h = { (_Float16)wv.x, (_Float16)wv.y, (_Float16)wv.z, (_Float16)wv.w };
            *(half4v*)&As[row * 72 + c4] = h;
        }
        // stage B: transpose z[kb+k][n0+n] -> Bs[n][k], XOR-swizzled rows.
        // Each thread: 2 adjacent k-rows x 8 n -> 8 packed b32 writes (2-way max).
        {
            int ci2 = tid >> 3, nb8 = tid & 7;  // ci2: 0..31 (k pair), nb8: n block
            int c0 = 2 * ci2;
            const size_t zrow = ((size_t)b * NC + kb + c0) * HW + n0 + nb8 * 8;
            half8v g0 = *(const half8v*)&zt[zrow];
            half8v g1 = *(const half8v*)&zt[zrow + HW];
            ushort8v u0 = (ushort8v)g0;
            ushort8v u1 = (ushort8v)g1;
            #pragma unroll
            for (int t = 0; t < 8; ++t) {
                int n = nb8 * 8 + t;
                unsigned v = (unsigned)u0[t] | ((unsigned)u1[t] << 16);
                int boff = (n * 144 + c0 * 2) ^ (nb8 << 4);
                *(unsigned*)((char*)Bs + boff) = v;
            }
        }
        __syncthreads();
        #pragma unroll
        for (int q = 0; q < 2; ++q) {
            const int kq = q * 32 + quad * 8;   // lane's k start within BK
            half8v af[4], bf[2];
            #pragma unroll
            for (int i = 0; i < 4; ++i)
                af[i] = *(const half8v*)&As[(wm + i * 16 + l15) * 72 + kq];
            #pragma unroll
            for (int j = 0; j < 2; ++j) {
                int n = wn + j * 16 + l15;
                int roff = (n * 144 + kq * 2) ^ (((n >> 3) & 7) << 4);
                bf[j] = *(const half8v*)((const char*)Bs + roff);
            }
            #pragma unroll
            for (int i = 0; i < 4; ++i)
                #pragma unroll
                for (int j = 0; j < 2; ++j)
                    acc[i][j] = __builtin_amdgcn_mfma_f32_16x16x32_f16(af[i], bf[j], acc[i][j], 0, 0, 0);
        }
    }
    // epilogue: D row = quad*4+r, col = l15
    #pragma unroll
    for (int i = 0; i < 4; ++i) {
        #pragma unroll
        for (int r = 0; r < 4; ++r) {
            int o = m0 + wm + i * 16 + quad * 4 + r;
            size_t rowbase = ((size_t)b * NC + o) * HW + n0;
            #pragma unroll
            for (int j = 0; j < 2; ++j) {
                int n = wn + j * 16 + l15;
                out[rowbase + n] = acc[i][j][r] + skip[rowbase + n];
            }
        }
    }
}

extern "C" void kernel_launch(void* const* d_in, const int* in_sizes, int n_in,
                              void* d_out, int out_size, void* d_ws, size_t ws_size,
                              hipStream_t stream) {
    const float* skip = (const float*)d_in[0];
    const float* dec  = (const float*)d_in[1];
    const float* wfea = (const float*)d_in[2];
    const float* sg1  = (const float*)d_in[3];
    const float* sg2  = (const float*)d_in[4];
    const float* W    = (const float*)d_in[5];
    float* out = (float*)d_out;
    _Float16* zt = (_Float16*)d_ws;   // 75.5 MB: [16][256][9216] f16

    stage1_kernel<<<NB * 64, 512, 0, stream>>>(skip, dec, wfea, sg1, sg2, zt);
    gemm_kernel<<<16 * 288, 256, 0, stream>>>(zt, W, skip, out);
}

// Round 3
// 485.588 us; speedup vs baseline: 1.2743x; 1.0636x over previous
//
#include <hip/hip_runtime.h>
#include <cstdint>
#include <cmath>

typedef _Float16 half4v __attribute__((ext_vector_type(4)));
typedef _Float16 half8v __attribute__((ext_vector_type(8)));
typedef unsigned short ushort8v __attribute__((ext_vector_type(8)));
typedef float float4v __attribute__((ext_vector_type(4)));
typedef float float2v __attribute__((ext_vector_type(2)));

#define NB 16
#define NC 256
#define HW 9216   // 96*96

// ---------------------------------------------------------------------------
// Stage 1: y = dec+skip; z = 3y + w_fea*w_edge(y) + DoG(y); zt[b][c][hw] f16.
// 4 pixels/thread: b128 neighbor reads, shared bilinear taps, closed-form
// index/weight math (no tables). Register prefetch of next channel.
// LDS 69120 B -> 2 blocks/CU.
// ---------------------------------------------------------------------------
__global__ __launch_bounds__(512, 4) void stage1_kernel(
    const float* __restrict__ skip, const float* __restrict__ dec,
    const float* __restrict__ wfea, const float* __restrict__ sig1,
    const float* __restrict__ sig2, _Float16* __restrict__ zt) {
    __shared__ __align__(16) float sy[HW];          // 36864 B
    __shared__ __align__(16) float d72b[72 * 72];   // 20736 B
    __shared__ __align__(16) float d48b[48 * 48];   //  9216 B
    __shared__ __align__(16) float d24b[24 * 24];   //  2304 B  total 69120 B

    const int tid = threadIdx.x;
    const int b = blockIdx.x >> 6;
    const int cg = blockIdx.x & 63;

    // prefetch channel cg*4+0
    const float4* dp0 = (const float4*)(dec + ((size_t)b * NC + cg * 4) * HW);
    const float4* sp0 = (const float4*)(skip + ((size_t)b * NC + cg * 4) * HW);
    float4 pd[5], ps[5];
    #pragma unroll
    for (int it = 0; it < 5; ++it) {
        int g = tid + it * 512;
        if (g < 2304) { pd[it] = dp0[g]; ps[it] = sp0[g]; }
    }

    for (int cc = 0; cc < 4; ++cc) {
        const int c = cg * 4 + cc;
        const size_t base = ((size_t)b * NC + c) * HW;
        __syncthreads();   // previous channel done reading sy/d*
        // ---- write y = dec + skip from prefetch regs ----
        #pragma unroll
        for (int it = 0; it < 5; ++it) {
            int g = tid + it * 512;
            if (g < 2304) {
                float4 a = pd[it], s = ps[it];
                float4v v = {a.x + s.x, a.y + s.y, a.z + s.z, a.w + s.w};
                *(float4v*)&sy[g * 4] = v;
            }
        }
        // ---- issue next channel's loads (land during pixel phase) ----
        if (cc < 3) {
            const float4* dpn = (const float4*)(dec + base + HW);
            const float4* spn = (const float4*)(skip + base + HW);
            #pragma unroll
            for (int it = 0; it < 5; ++it) {
                int g = tid + it * 512;
                if (g < 2304) { pd[it] = dpn[g]; ps[it] = spn[g]; }
            }
        }
        __syncthreads();   // sy ready
        // ---- downsamples ----
        // 96->48: avg of 2x2 (rows 2o,2o+1)
        for (int i = tid; i < 48 * 48; i += 512) {
            int oy = i / 48, ox = i - oy * 48;
            float2v a = *(const float2v*)&sy[oy * 192 + ox * 2];
            float2v bb = *(const float2v*)&sy[oy * 192 + 96 + ox * 2];
            d48b[i] = 0.25f * (a[0] + a[1] + bb[0] + bb[1]);
        }
        // 96->24: avg of 2x2 at rows/cols (4o+1,4o+2); b128 then use lanes 1,2
        for (int i = tid; i < 24 * 24; i += 512) {
            int oy = i / 24, ox = i - oy * 24;
            float4v t = *(const float4v*)&sy[(4 * oy + 1) * 96 + 4 * ox];
            float4v u = *(const float4v*)&sy[(4 * oy + 2) * 96 + 4 * ox];
            d24b[i] = 0.25f * (t[1] + t[2] + u[1] + u[2]);
        }
        // 96->72: src=(8o+1)/6
        for (int i = tid; i < 72 * 72; i += 512) {
            int oy = i / 72, ox = i - oy * 72;
            int qy = oy / 3, ry = oy - qy * 3;
            int qx = ox / 3, rx = ox - qx * 3;
            int iy = 4 * qy + ry, ix = 4 * qx + rx;
            float fy = (ry == 0) ? 0.16666667f : (ry == 1 ? 0.5f : 0.83333333f);
            float fx = (rx == 0) ? 0.16666667f : (rx == 1 ? 0.5f : 0.83333333f);
            const float* r0 = &sy[iy * 96 + ix];
            float v0 = r0[0] + fx * (r0[1] - r0[0]);
            float v1 = r0[96] + fx * (r0[97] - r0[96]);
            d72b[i] = v0 + fy * (v1 - v0);
        }
        // ---- per-channel params ----
        float wf = wfea[c];
        float sgA = 2.f / (1.f + expf(-sig1[c]));
        float sgB = 2.f / (1.f + expf(-sig2[c]));
        float eA = expf(-0.5f / (sgA * sgA));
        float eB = expf(-0.5f / (sgB * sgB));
        float nA = 1.f + 4.f * eA + 4.f * eA * eA;
        float nB = 1.f + 4.f * eB + 4.f * eB * eB;
        float k0 = 1.f / nA - 1.f / nB;
        float k1 = eA / nA - eB / nB;
        float k2 = eA * eA / nA - eB * eB / nB;
        __syncthreads();   // d* ready
        // ---- pixel phase: 4 consecutive pixels per thread ----
        #pragma unroll 1
        for (int it = 0; it < 5; ++it) {
            int g = tid + it * 512;          // group id, pixels 4g..4g+3
            if (g >= 2304) break;
            int h = g / 24, xg = g - h * 24; // xg in [0,24), x0 = 4*xg
            int x0 = xg * 4;
            int rbase = h * 96 + x0;
            // neighbor rows (zero-padded)
            float4v vc = *(const float4v*)&sy[rbase];
            float lc = (xg > 0) ? sy[rbase - 1] : 0.f;
            float rc = (xg < 23) ? sy[rbase + 4] : 0.f;
            float4v vm, vp; float lm, rm, lp, rp;
            if (h > 0) {
                vm = *(const float4v*)&sy[rbase - 96];
                lm = (xg > 0) ? sy[rbase - 97] : 0.f;
                rm = (xg < 23) ? sy[rbase - 92] : 0.f;
            } else { vm = (float4v){0.f, 0.f, 0.f, 0.f}; lm = 0.f; rm = 0.f; }
            if (h < 95) {
                vp = *(const float4v*)&sy[rbase + 96];
                lp = (xg > 0) ? sy[rbase + 95] : 0.f;
                rp = (xg < 23) ? sy[rbase + 100] : 0.f;
            } else { vp = (float4v){0.f, 0.f, 0.f, 0.f}; lp = 0.f; rp = 0.f; }
            // row indices/weights per scale (closed form, half-pixel)
            int i24 = (h - 2) >> 2; int ya24 = i24 < 0 ? 0 : i24; int yb24 = (i24 + 1 > 23) ? 23 : i24 + 1;
            float fy24 = (h & 2) ? ((h & 1) ? 0.375f : 0.125f) : ((h & 1) ? 0.875f : 0.625f);
            int i48 = (h - 1) >> 1; int ya48 = i48 < 0 ? 0 : i48; int yb48 = (i48 + 1 > 47) ? 47 : i48 + 1;
            float fy48 = (h & 1) ? 0.25f : 0.75f;
            int i72 = (3 * h - 1) >> 2; int ya72 = i72 < 0 ? 0 : i72; int yb72 = (i72 + 1 > 71) ? 71 : i72 + 1;
            float fy72 = (h & 2) ? ((h & 1) ? 0.125f : 0.375f) : ((h & 1) ? 0.625f : 0.875f);
            // 24-grid taps: cols {xg-1, xg, xg+1} clamped
            int a24 = xg > 0 ? xg - 1 : 0;
            int c24c = xg < 23 ? xg + 1 : 23;
            const float* t24r = &d24b[ya24 * 24];
            const float* b24r = &d24b[yb24 * 24];
            float q00 = t24r[a24], q01 = t24r[xg], q02 = t24r[c24c];
            float q10 = b24r[a24], q11 = b24r[xg], q12 = b24r[c24c];
            // 48-grid taps: cols {c48-1..c48+2} clamped
            int c48 = 2 * xg;
            int a48 = c48 > 0 ? c48 - 1 : 0;
            int e48 = (c48 + 2 > 47) ? 47 : c48 + 2;
            const float* t48r = &d48b[ya48 * 48];
            const float* b48r = &d48b[yb48 * 48];
            float r00 = t48r[a48], r01 = t48r[c48], r02 = t48r[c48 + 1], r03 = t48r[e48];
            float r10 = b48r[a48], r11 = b48r[c48], r12 = b48r[c48 + 1], r13 = b48r[e48];
            // 72-grid taps: cols {c72-1..c72+3} clamped
            int c72 = 3 * xg;
            int a72 = c72 > 0 ? c72 - 1 : 0;
            int e72 = (c72 + 3 > 71) ? 71 : c72 + 3;
            const float* t72r = &d72b[ya72 * 72];
            const float* b72r = &d72b[yb72 * 72];
            float s00 = t72r[a72], s01 = t72r[c72], s02 = t72r[c72 + 1], s03 = t72r[c72 + 2], s04 = t72r[e72];
            float s10 = b72r[a72], s11 = b72r[c72], s12 = b72r[c72 + 1], s13 = b72r[c72 + 2], s14 = b72r[e72];

            auto bl2 = [](float ta, float tb, float ba, float bb_, float fx, float fy) {
                float t = ta + fx * (tb - ta);
                float u = ba + fx * (bb_ - ba);
                return t + fy * (u - t);
            };
            float u24_0 = bl2(q00, q01, q10, q11, 0.625f, fy24);
            float u24_1 = bl2(q00, q01, q10, q11, 0.875f, fy24);
            float u24_2 = bl2(q01, q02, q11, q12, 0.125f, fy24);
            float u24_3 = bl2(q01, q02, q11, q12, 0.375f, fy24);
            float u48_0 = bl2(r00, r01, r10, r11, 0.75f, fy48);
            float u48_1 = bl2(r01, r02, r11, r12, 0.25f, fy48);
            float u48_2 = bl2(r01, r02, r11, r12, 0.75f, fy48);
            float u48_3 = bl2(r02, r03, r12, r13, 0.25f, fy48);
            float u72_0 = bl2(s00, s01, s10, s11, 0.875f, fy72);
            float u72_1 = bl2(s01, s02, s11, s12, 0.625f, fy72);
            float u72_2 = bl2(s02, s03, s12, s13, 0.375f, fy72);
            float u72_3 = bl2(s03, s04, s13, s14, 0.125f, fy72);

            auto pix = [&](float yv, float u24, float u48, float u72,
                           float ns, float cs) -> _Float16 {
                float e0 = fabsf(yv - u24);
                float e1 = fabsf(yv - u48);
                float e2 = fabsf(yv - u72);
                float we = (fabsf(e0 - e1) + fabsf(e0 - e2) + fabsf(e1 - e2)) * (1.f / 3.f);
                float z = 3.f * yv + wf * we + k0 * yv + k1 * ns + k2 * cs;
                return (_Float16)z;
            };
            half4v zv;
            zv[0] = pix(vc[0], u24_0, u48_0, u72_0, vm[0] + vp[0] + lc + vc[1],
                        lm + vm[1] + lp + vp[1]);
            zv[1] = pix(vc[1], u24_1, u48_1, u72_1, vm[1] + vp[1] + vc[0] + vc[2],
                        vm[0] + vm[2] + vp[0] + vp[2]);
            zv[2] = pix(vc[2], u24_2, u48_2, u72_2, vm[2] + vp[2] + vc[1] + vc[3],
                        vm[1] + vm[3] + vp[1] + vp[3]);
            zv[3] = pix(vc[3], u24_3, u48_3, u72_3, vm[3] + vp[3] + vc[2] + rc,
                        vm[2] + rm + vp[2] + rp);
            *(half4v*)&zt[base + (size_t)g * 4] = zv;
        }
    }
}

// ---------------------------------------------------------------------------
// Stage 2: out[b,o,n] = sum_c W[o,c] * z[b,c,n] + skip[b,o,n]
// BM=256 (full M) x BN=64, BK=64; 256 thr = 4 waves, wave tile 64x64.
// zt read exactly once (75.5 MB). XOR-swizzled As/Bs, LDS 40960 B ->
// 3 blocks/CU. Next-kt B-tile global loads issued before MFMA (latency hide).
// ---------------------------------------------------------------------------
__global__ __launch_bounds__(256, 3) void gemm_kernel(
    const _Float16* __restrict__ zt, const float* __restrict__ W,
    const float* __restrict__ skip, float* __restrict__ out) {
    __shared__ __align__(16) _Float16 As[256 * 64];   // 32768 B, XOR swizzle
    __shared__ __align__(16) _Float16 Bs[64 * 64];    //  8192 B, XOR swizzle

    const int tid = threadIdx.x;
    const int bid = blockIdx.x;
    const int ni = bid % 144;                // 9216/64 n-tiles
    const int b  = bid / 144;
    const int n0 = ni * 64;
    const int lane = tid & 63;
    const int w = tid >> 6;                  // 0..3
    const int wm = w * 64;
    const int l15 = lane & 15;
    const int quad = lane >> 4;

    float4v acc[4][4];
    #pragma unroll
    for (int i = 0; i < 4; ++i)
        #pragma unroll
        for (int j = 0; j < 4; ++j)
            acc[i][j] = (float4v){0.f, 0.f, 0.f, 0.f};

    // B prefetch: thread owns k-pair (c0,c0+1) x 8 n
    const int ci2 = tid >> 3, nb8 = tid & 7;
    const int c0 = 2 * ci2;
    const size_t zbase = ((size_t)b * NC + c0) * HW + n0 + nb8 * 8;
    half8v bg0 = *(const half8v*)&zt[zbase];
    half8v bg1 = *(const half8v*)&zt[zbase + HW];

    for (int kt = 0; kt < 4; ++kt) {
        const int kb = kt * 64;
        __syncthreads();
        // ---- write B tile (transposed, swizzled): Bs[n][k] ----
        {
            ushort8v u0 = (ushort8v)bg0, u1 = (ushort8v)bg1;
            #pragma unroll
            for (int t = 0; t < 8; ++t) {
                int n = nb8 * 8 + t;
                unsigned v = (unsigned)u0[t] | ((unsigned)u1[t] << 16);
                int boff = (n * 128 + c0 * 2) ^ ((n & 7) << 4);
                *(unsigned*)((char*)Bs + boff) = v;
            }
        }
        // ---- stage A: W[0:256][kb:kb+64] f32 -> f16, swizzled [m][k] ----
        #pragma unroll
        for (int p = 0; p < 16; ++p) {
            int idx = tid + p * 256;            // 0..4095
            int row = idx >> 4, c4 = (idx & 15) << 2;
            float4 wv = *(const float4*)&W[row * 256 + kb + c4];
            half4v hv = { (_Float16)wv.x, (_Float16)wv.y, (_Float16)wv.z, (_Float16)wv.w };
            int aoff = (row * 128 + c4 * 2) ^ ((row & 7) << 4);
            *(half4v*)((char*)As + aoff) = hv;
        }
        __syncthreads();
        // ---- prefetch next kt's B-tile globals (hide under MFMA) ----
        if (kt < 3) {
            const size_t znext = zbase + (size_t)(kb + 64) * HW;
            bg0 = *(const half8v*)&zt[znext];
            bg1 = *(const half8v*)&zt[znext + HW];
        }
        // ---- MFMA ----
        #pragma unroll
        for (int q = 0; q < 2; ++q) {
            const int kq = q * 32 + quad * 8;
            half8v af[4], bf[4];
            #pragma unroll
            for (int i = 0; i < 4; ++i) {
                int row = wm + i * 16 + l15;
                int off = (row * 128 + kq * 2) ^ ((row & 7) << 4);
                af[i] = *(const half8v*)((const char*)As + off);
            }
            #pragma unroll
            for (int j = 0; j < 4; ++j) {
                int n = j * 16 + l15;
                int off = (n * 128 + kq * 2) ^ ((n & 7) << 4);
                bf[j] = *(const half8v*)((const char*)Bs + off);
            }
            #pragma unroll
            for (int i = 0; i < 4; ++i)
                #pragma unroll
                for (int j = 0; j < 4; ++j)
                    acc[i][j] = __builtin_amdgcn_mfma_f32_16x16x32_f16(af[i], bf[j], acc[i][j], 0, 0, 0);
        }
    }
    // epilogue: D row = quad*4+r, col = l15
    #pragma unroll
    for (int i = 0; i < 4; ++i) {
        #pragma unroll
        for (int r = 0; r < 4; ++r) {
            int o = wm + i * 16 + quad * 4 + r;
            size_t rowbase = ((size_t)b * NC + o) * HW + n0;
            #pragma unroll
            for (int j = 0; j < 4; ++j) {
                int n = j * 16 + l15;
                out[rowbase + n] = acc[i][j][r] + skip[rowbase + n];
            }
        }
    }
}

extern "C" void kernel_launch(void* const* d_in, const int* in_sizes, int n_in,
                              void* d_out, int out_size, void* d_ws, size_t ws_size,
                              hipStream_t stream) {
    const float* skip = (const float*)d_in[0];
    const float* dec  = (const float*)d_in[1];
    const float* wfea = (const float*)d_in[2];
    const float* sg1  = (const float*)d_in[3];
    const float* sg2  = (const float*)d_in[4];
    const float* W    = (const float*)d_in[5];
    float* out = (float*)d_out;
    _Float16* zt = (_Float16*)d_ws;   // 75.5 MB: [16][256][9216] f16

    stage1_kernel<<<NB * 64, 512, 0, stream>>>(skip, dec, wfea, sg1, sg2, zt);
    gemm_kernel<<<144 * NB, 256, 0, stream>>>(zt, W, skip, out);
}

// Round 4
// 475.465 us; speedup vs baseline: 1.3014x; 1.0213x over previous
//
#include <hip/hip_runtime.h>
#include <cstdint>
#include <cmath>

typedef _Float16 half4v __attribute__((ext_vector_type(4)));
typedef _Float16 half8v __attribute__((ext_vector_type(8)));
typedef unsigned short ushort8v __attribute__((ext_vector_type(8)));
typedef float float4v __attribute__((ext_vector_type(4)));
typedef float float2v __attribute__((ext_vector_type(2)));

#define NB 16
#define NC 256
#define HW 9216   // 96*96

// ---------------------------------------------------------------------------
// Stage 1 (UNCHANGED from R3 — control for this round's A/B on stage2)
// ---------------------------------------------------------------------------
__global__ __launch_bounds__(512, 4) void stage1_kernel(
    const float* __restrict__ skip, const float* __restrict__ dec,
    const float* __restrict__ wfea, const float* __restrict__ sig1,
    const float* __restrict__ sig2, _Float16* __restrict__ zt) {
    __shared__ __align__(16) float sy[HW];          // 36864 B
    __shared__ __align__(16) float d72b[72 * 72];   // 20736 B
    __shared__ __align__(16) float d48b[48 * 48];   //  9216 B
    __shared__ __align__(16) float d24b[24 * 24];   //  2304 B  total 69120 B

    const int tid = threadIdx.x;
    const int b = blockIdx.x >> 6;
    const int cg = blockIdx.x & 63;

    // prefetch channel cg*4+0
    const float4* dp0 = (const float4*)(dec + ((size_t)b * NC + cg * 4) * HW);
    const float4* sp0 = (const float4*)(skip + ((size_t)b * NC + cg * 4) * HW);
    float4 pd[5], ps[5];
    #pragma unroll
    for (int it = 0; it < 5; ++it) {
        int g = tid + it * 512;
        if (g < 2304) { pd[it] = dp0[g]; ps[it] = sp0[g]; }
    }

    for (int cc = 0; cc < 4; ++cc) {
        const int c = cg * 4 + cc;
        const size_t base = ((size_t)b * NC + c) * HW;
        __syncthreads();   // previous channel done reading sy/d*
        // ---- write y = dec + skip from prefetch regs ----
        #pragma unroll
        for (int it = 0; it < 5; ++it) {
            int g = tid + it * 512;
            if (g < 2304) {
                float4 a = pd[it], s = ps[it];
                float4v v = {a.x + s.x, a.y + s.y, a.z + s.z, a.w + s.w};
                *(float4v*)&sy[g * 4] = v;
            }
        }
        // ---- issue next channel's loads (land during pixel phase) ----
        if (cc < 3) {
            const float4* dpn = (const float4*)(dec + base + HW);
            const float4* spn = (const float4*)(skip + base + HW);
            #pragma unroll
            for (int it = 0; it < 5; ++it) {
                int g = tid + it * 512;
                if (g < 2304) { pd[it] = dpn[g]; ps[it] = spn[g]; }
            }
        }
        __syncthreads();   // sy ready
        // ---- downsamples ----
        for (int i = tid; i < 48 * 48; i += 512) {
            int oy = i / 48, ox = i - oy * 48;
            float2v a = *(const float2v*)&sy[oy * 192 + ox * 2];
            float2v bb = *(const float2v*)&sy[oy * 192 + 96 + ox * 2];
            d48b[i] = 0.25f * (a[0] + a[1] + bb[0] + bb[1]);
        }
        for (int i = tid; i < 24 * 24; i += 512) {
            int oy = i / 24, ox = i - oy * 24;
            float4v t = *(const float4v*)&sy[(4 * oy + 1) * 96 + 4 * ox];
            float4v u = *(const float4v*)&sy[(4 * oy + 2) * 96 + 4 * ox];
            d24b[i] = 0.25f * (t[1] + t[2] + u[1] + u[2]);
        }
        for (int i = tid; i < 72 * 72; i += 512) {
            int oy = i / 72, ox = i - oy * 72;
            int qy = oy / 3, ry = oy - qy * 3;
            int qx = ox / 3, rx = ox - qx * 3;
            int iy = 4 * qy + ry, ix = 4 * qx + rx;
            float fy = (ry == 0) ? 0.16666667f : (ry == 1 ? 0.5f : 0.83333333f);
            float fx = (rx == 0) ? 0.16666667f : (rx == 1 ? 0.5f : 0.83333333f);
            const float* r0 = &sy[iy * 96 + ix];
            float v0 = r0[0] + fx * (r0[1] - r0[0]);
            float v1 = r0[96] + fx * (r0[97] - r0[96]);
            d72b[i] = v0 + fy * (v1 - v0);
        }
        // ---- per-channel params ----
        float wf = wfea[c];
        float sgA = 2.f / (1.f + expf(-sig1[c]));
        float sgB = 2.f / (1.f + expf(-sig2[c]));
        float eA = expf(-0.5f / (sgA * sgA));
        float eB = expf(-0.5f / (sgB * sgB));
        float nA = 1.f + 4.f * eA + 4.f * eA * eA;
        float nB = 1.f + 4.f * eB + 4.f * eB * eB;
        float k0 = 1.f / nA - 1.f / nB;
        float k1 = eA / nA - eB / nB;
        float k2 = eA * eA / nA - eB * eB / nB;
        __syncthreads();   // d* ready
        // ---- pixel phase: 4 consecutive pixels per thread ----
        #pragma unroll 1
        for (int it = 0; it < 5; ++it) {
            int g = tid + it * 512;
            if (g >= 2304) break;
            int h = g / 24, xg = g - h * 24;
            int x0 = xg * 4;
            int rbase = h * 96 + x0;
            float4v vc = *(const float4v*)&sy[rbase];
            float lc = (xg > 0) ? sy[rbase - 1] : 0.f;
            float rc = (xg < 23) ? sy[rbase + 4] : 0.f;
            float4v vm, vp; float lm, rm, lp, rp;
            if (h > 0) {
                vm = *(const float4v*)&sy[rbase - 96];
                lm = (xg > 0) ? sy[rbase - 97] : 0.f;
                rm = (xg < 23) ? sy[rbase - 92] : 0.f;
            } else { vm = (float4v){0.f, 0.f, 0.f, 0.f}; lm = 0.f; rm = 0.f; }
            if (h < 95) {
                vp = *(const float4v*)&sy[rbase + 96];
                lp = (xg > 0) ? sy[rbase + 95] : 0.f;
                rp = (xg < 23) ? sy[rbase + 100] : 0.f;
            } else { vp = (float4v){0.f, 0.f, 0.f, 0.f}; lp = 0.f; rp = 0.f; }
            int i24 = (h - 2) >> 2; int ya24 = i24 < 0 ? 0 : i24; int yb24 = (i24 + 1 > 23) ? 23 : i24 + 1;
            float fy24 = (h & 2) ? ((h & 1) ? 0.375f : 0.125f) : ((h & 1) ? 0.875f : 0.625f);
            int i48 = (h - 1) >> 1; int ya48 = i48 < 0 ? 0 : i48; int yb48 = (i48 + 1 > 47) ? 47 : i48 + 1;
            float fy48 = (h & 1) ? 0.25f : 0.75f;
            int i72 = (3 * h - 1) >> 2; int ya72 = i72 < 0 ? 0 : i72; int yb72 = (i72 + 1 > 71) ? 71 : i72 + 1;
            float fy72 = (h & 2) ? ((h & 1) ? 0.125f : 0.375f) : ((h & 1) ? 0.625f : 0.875f);
            int a24 = xg > 0 ? xg - 1 : 0;
            int c24c = xg < 23 ? xg + 1 : 23;
            const float* t24r = &d24b[ya24 * 24];
            const float* b24r = &d24b[yb24 * 24];
            float q00 = t24r[a24], q01 = t24r[xg], q02 = t24r[c24c];
            float q10 = b24r[a24], q11 = b24r[xg], q12 = b24r[c24c];
            int c48 = 2 * xg;
            int a48 = c48 > 0 ? c48 - 1 : 0;
            int e48 = (c48 + 2 > 47) ? 47 : c48 + 2;
            const float* t48r = &d48b[ya48 * 48];
            const float* b48r = &d48b[yb48 * 48];
            float r00 = t48r[a48], r01 = t48r[c48], r02 = t48r[c48 + 1], r03 = t48r[e48];
            float r10 = b48r[a48], r11 = b48r[c48], r12 = b48r[c48 + 1], r13 = b48r[e48];
            int c72 = 3 * xg;
            int a72 = c72 > 0 ? c72 - 1 : 0;
            int e72 = (c72 + 3 > 71) ? 71 : c72 + 3;
            const float* t72r = &d72b[ya72 * 72];
            const float* b72r = &d72b[yb72 * 72];
            float s00 = t72r[a72], s01 = t72r[c72], s02 = t72r[c72 + 1], s03 = t72r[c72 + 2], s04 = t72r[e72];
            float s10 = b72r[a72], s11 = b72r[c72], s12 = b72r[c72 + 1], s13 = b72r[c72 + 2], s14 = b72r[e72];

            auto bl2 = [](float ta, float tb, float ba, float bb_, float fx, float fy) {
                float t = ta + fx * (tb - ta);
                float u = ba + fx * (bb_ - ba);
                return t + fy * (u - t);
            };
            float u24_0 = bl2(q00, q01, q10, q11, 0.625f, fy24);
            float u24_1 = bl2(q00, q01, q10, q11, 0.875f, fy24);
            float u24_2 = bl2(q01, q02, q11, q12, 0.125f, fy24);
            float u24_3 = bl2(q01, q02, q11, q12, 0.375f, fy24);
            float u48_0 = bl2(r00, r01, r10, r11, 0.75f, fy48);
            float u48_1 = bl2(r01, r02, r11, r12, 0.25f, fy48);
            float u48_2 = bl2(r01, r02, r11, r12, 0.75f, fy48);
            float u48_3 = bl2(r02, r03, r12, r13, 0.25f, fy48);
            float u72_0 = bl2(s00, s01, s10, s11, 0.875f, fy72);
            float u72_1 = bl2(s01, s02, s11, s12, 0.625f, fy72);
            float u72_2 = bl2(s02, s03, s12, s13, 0.375f, fy72);
            float u72_3 = bl2(s03, s04, s13, s14, 0.125f, fy72);

            auto pix = [&](float yv, float u24, float u48, float u72,
                           float ns, float cs) -> _Float16 {
                float e0 = fabsf(yv - u24);
                float e1 = fabsf(yv - u48);
                float e2 = fabsf(yv - u72);
                float we = (fabsf(e0 - e1) + fabsf(e0 - e2) + fabsf(e1 - e2)) * (1.f / 3.f);
                float z = 3.f * yv + wf * we + k0 * yv + k1 * ns + k2 * cs;
                return (_Float16)z;
            };
            half4v zv;
            zv[0] = pix(vc[0], u24_0, u48_0, u72_0, vm[0] + vp[0] + lc + vc[1],
                        lm + vm[1] + lp + vp[1]);
            zv[1] = pix(vc[1], u24_1, u48_1, u72_1, vm[1] + vp[1] + vc[0] + vc[2],
                        vm[0] + vm[2] + vp[0] + vp[2]);
            zv[2] = pix(vc[2], u24_2, u48_2, u72_2, vm[2] + vp[2] + vc[1] + vc[3],
                        vm[1] + vm[3] + vp[1] + vp[3]);
            zv[3] = pix(vc[3], u24_3, u48_3, u72_3, vm[3] + vp[3] + vc[2] + rc,
                        vm[2] + rm + vp[2] + rp);
            *(half4v*)&zt[base + (size_t)g * 4] = zv;
        }
    }
}

// ---------------------------------------------------------------------------
// W prep: f32 [256][256] -> f16, pre-swizzled per-BK64-tile LDS image.
// Wh byte layout: [kt][ (row*128 + kk*2) ^ ((row&7)<<4) ], tile = 32768 B.
// ---------------------------------------------------------------------------
__global__ __launch_bounds__(256) void wprep_kernel(
    const float* __restrict__ W, _Float16* __restrict__ Wh) {
    int row = blockIdx.x;          // 0..255
    int t = threadIdx.x;           // 0..255 (k)
    float v = W[row * 256 + t];
    int kt = t >> 6, kk = t & 63;
    int off = kt * 32768 + ((row * 128 + kk * 2) ^ ((row & 7) << 4));
    *(_Float16*)((char*)Wh + off) = (_Float16)v;
}

__device__ inline void gload_lds16(const void* g, void* lds) {
    __builtin_amdgcn_global_load_lds(
        (const __attribute__((address_space(1))) unsigned int*)g,
        (__attribute__((address_space(3))) unsigned int*)lds,
        16, 0, 0);
}

// ---------------------------------------------------------------------------
// Stage 2: out[b,o,n] = sum_c W[o,c] * z[b,c,n] + skip[b,o,n]
// BM=256 x BN=64, BK=64; 256 thr = 4 waves, wave tile 64x64; LDS 40960 B.
// PRE=1: A staged via 8x global_load_lds_dwordx4 from pre-swizzled Wh
// (no f32 loads, no cvt, no A ds_writes). PRE=0: R3 fallback.
// ---------------------------------------------------------------------------
template <int PRE>
__global__ __launch_bounds__(256, 4) void gemm_kernel(
    const _Float16* __restrict__ zt, const float* __restrict__ W,
    const _Float16* __restrict__ Wh,
    const float* __restrict__ skip, float* __restrict__ out) {
    __shared__ __align__(16) _Float16 As[256 * 64];   // 32768 B, XOR swizzle
    __shared__ __align__(16) _Float16 Bs[64 * 64];    //  8192 B, XOR swizzle

    const int tid = threadIdx.x;
    const int bid = blockIdx.x;
    const int ni = bid % 144;
    const int b  = bid / 144;
    const int n0 = ni * 64;
    const int lane = tid & 63;
    const int w = tid >> 6;                  // 0..3
    const int wm = w * 64;
    const int l15 = lane & 15;
    const int quad = lane >> 4;

    float4v acc[4][4];
    #pragma unroll
    for (int i = 0; i < 4; ++i)
        #pragma unroll
        for (int j = 0; j < 4; ++j)
            acc[i][j] = (float4v){0.f, 0.f, 0.f, 0.f};

    // B prefetch: thread owns k-pair (c0,c0+1) x 8 n
    const int ci2 = tid >> 3, nb8 = tid & 7;
    const int c0 = 2 * ci2;
    const size_t zbase = ((size_t)b * NC + c0) * HW + n0 + nb8 * 8;
    half8v bg0 = *(const half8v*)&zt[zbase];
    half8v bg1 = *(const half8v*)&zt[zbase + HW];

    for (int kt = 0; kt < 4; ++kt) {
        const int kb = kt * 64;
        __syncthreads();
        // ---- write B tile (transposed, swizzled): Bs[n][k] ----
        {
            ushort8v u0 = (ushort8v)bg0, u1 = (ushort8v)bg1;
            #pragma unroll
            for (int t = 0; t < 8; ++t) {
                int n = nb8 * 8 + t;
                unsigned v = (unsigned)u0[t] | ((unsigned)u1[t] << 16);
                int boff = (n * 128 + c0 * 2) ^ ((n & 7) << 4);
                *(unsigned*)((char*)Bs + boff) = v;
            }
        }
        // ---- stage A ----
        if (PRE) {
            // async DMA: pre-swizzled Wh tile -> As, linear, 1 KB per wave-issue
            const char* wsrc = (const char*)Wh + kt * 32768 + w * 8192 + lane * 16;
            char* adst = (char*)As + w * 8192;
            #pragma unroll
            for (int i = 0; i < 8; ++i)
                gload_lds16(wsrc + i * 1024, adst + i * 1024);
        } else {
            #pragma unroll
            for (int p = 0; p < 16; ++p) {
                int idx = tid + p * 256;
                int row = idx >> 4, c4 = (idx & 15) << 2;
                float4 wv = *(const float4*)&W[row * 256 + kb + c4];
                half4v hv = { (_Float16)wv.x, (_Float16)wv.y, (_Float16)wv.z, (_Float16)wv.w };
                int aoff = (row * 128 + c4 * 2) ^ ((row & 7) << 4);
                *(half4v*)((char*)As + aoff) = hv;
            }
        }
        __syncthreads();   // drains vmcnt (incl. gload_lds) + lgkm
        // ---- prefetch next kt's B-tile globals (hide under MFMA) ----
        if (kt < 3) {
            const size_t znext = zbase + (size_t)(kb + 64) * HW;
            bg0 = *(const half8v*)&zt[znext];
            bg1 = *(const half8v*)&zt[znext + HW];
        }
        // ---- MFMA ----
        #pragma unroll
        for (int q = 0; q < 2; ++q) {
            const int kq = q * 32 + quad * 8;
            half8v af[4], bf[4];
            #pragma unroll
            for (int i = 0; i < 4; ++i) {
                int row = wm + i * 16 + l15;
                int off = (row * 128 + kq * 2) ^ ((row & 7) << 4);
                af[i] = *(const half8v*)((const char*)As + off);
            }
            #pragma unroll
            for (int j = 0; j < 4; ++j) {
                int n = j * 16 + l15;
                int off = (n * 128 + kq * 2) ^ ((n & 7) << 4);
                bf[j] = *(const half8v*)((const char*)Bs + off);
            }
            #pragma unroll
            for (int i = 0; i < 4; ++i)
                #pragma unroll
                for (int j = 0; j < 4; ++j)
                    acc[i][j] = __builtin_amdgcn_mfma_f32_16x16x32_f16(af[i], bf[j], acc[i][j], 0, 0, 0);
        }
    }
    // epilogue: D row = quad*4+r, col = l15
    #pragma unroll
    for (int i = 0; i < 4; ++i) {
        #pragma unroll
        for (int r = 0; r < 4; ++r) {
            int o = wm + i * 16 + quad * 4 + r;
            size_t rowbase = ((size_t)b * NC + o) * HW + n0;
            #pragma unroll
            for (int j = 0; j < 4; ++j) {
                int n = j * 16 + l15;
                out[rowbase + n] = acc[i][j][r] + skip[rowbase + n];
            }
        }
    }
}

extern "C" void kernel_launch(void* const* d_in, const int* in_sizes, int n_in,
                              void* d_out, int out_size, void* d_ws, size_t ws_size,
                              hipStream_t stream) {
    const float* skip = (const float*)d_in[0];
    const float* dec  = (const float*)d_in[1];
    const float* wfea = (const float*)d_in[2];
    const float* sg1  = (const float*)d_in[3];
    const float* sg2  = (const float*)d_in[4];
    const float* W    = (const float*)d_in[5];
    float* out = (float*)d_out;
    _Float16* zt = (_Float16*)d_ws;                 // 75.5 MB: [16][256][9216] f16
    const size_t ZT_BYTES = (size_t)NB * NC * HW * 2;
    _Float16* Wh = (_Float16*)((char*)d_ws + ZT_BYTES);  // 128 KB pre-swizzled W

    stage1_kernel<<<NB * 64, 512, 0, stream>>>(skip, dec, wfea, sg1, sg2, zt);
    if (ws_size >= ZT_BYTES + 131072) {
        wprep_kernel<<<256, 256, 0, stream>>>(W, Wh);
        gemm_kernel<1><<<144 * NB, 256, 0, stream>>>(zt, W, Wh, skip, out);
    } else {
        gemm_kernel<0><<<144 * NB, 256, 0, stream>>>(zt, W, Wh, skip, out);
    }
}